// Round 1
// baseline (3548.396 us; speedup 1.0000x reference)
//
#include <hip/hip_runtime.h>
#include <stdint.h>

// Multi_LSTMs: bidirectional 4-head LSTM, BS=8 NT=128 CH=1024 H=512 G=2048.
// Plan:
//   pack x + weights to bf16 -> MFMA GEMM for input-to-hidden gates (fp32 out)
//   -> persistent recurrence kernel: 8 groups (dir,head) x 32 WGs; Whh slice
//      register-resident as MFMA B-frags; h state double-buffered in ws;
//      per-group monotonic counting barrier (agent-scope atomics).
// ws layout (peak ~105 MB):
//   [0,4K) barrier counters | [4K,136K) h state | [256K,320K) bias
//   [1M,65M) ih gates fp32 | [65M,73M) Xpack bf16 | [73M,105M) Wih bf16
//   after GEMM: [65M,81M) Whh bf16 (reuses Xpack/Wih region; stream-ordered)

typedef __attribute__((ext_vector_type(8))) short short8;
typedef __attribute__((ext_vector_type(4))) float floatx4;

__device__ __forceinline__ unsigned short f2bf(float f) {
  unsigned u = __float_as_uint(f);
  u = (u + 0x7fffu + ((u >> 16) & 1u)) >> 16;  // RNE
  return (unsigned short)u;
}
__device__ __forceinline__ float sigm(float x) { return 1.0f / (1.0f + __expf(-x)); }
__device__ __forceinline__ float tanh_f(float x) {
  float ax = fabsf(x);
  float e = __expf(-2.0f * ax);
  float t = (1.0f - e) / (1.0f + e);
  return x < 0.0f ? -t : t;
}

// x[8][128][1024][4] f32 -> Xp[4][1024][1024] bf16, row m = t*8+b
__global__ void pack_x_k(const float* __restrict__ x, unsigned short* __restrict__ Xp) {
  int g = blockIdx.x * 256 + threadIdx.x;  // m*1024 + c, < 1048576
  int m = g >> 10, c = g & 1023;
  int t = m >> 3, b = m & 7;
  float4 v = *(const float4*)(x + ((size_t)((b * 128 + t) * 1024 + c)) * 4);
  Xp[g]           = f2bf(v.x);
  Xp[1048576 + g] = f2bf(v.y);
  Xp[2097152 + g] = f2bf(v.z);
  Xp[3145728 + g] = f2bf(v.w);
}

__global__ void cast_bf_k(const float* __restrict__ src, unsigned short* __restrict__ dst, int n4) {
  int i = blockIdx.x * 256 + threadIdx.x;
  if (i >= n4) return;
  float4 v = ((const float4*)src)[i];
  ushort4 o;
  o.x = f2bf(v.x); o.y = f2bf(v.y); o.z = f2bf(v.z); o.w = f2bf(v.w);
  ((ushort4*)dst)[i] = o;
}

__global__ void bias_k(const float* __restrict__ bihf, const float* __restrict__ bhhf,
                       const float* __restrict__ bihb, const float* __restrict__ bhhb,
                       float* __restrict__ bias) {
  int i = blockIdx.x * 256 + threadIdx.x;  // < 16384 = 8 dk * 2048
  int dk = i >> 11, g = i & 2047, kk = dk & 3;
  const float* a = (dk < 4) ? bihf : bihb;
  const float* b = (dk < 4) ? bhhf : bhhb;
  bias[i] = a[kk * 2048 + g] + b[kk * 2048 + g];
}

// ih[dk][m][g] = sum_c Xp[kh][m][c] * Wb[dk][g][c] + bias[dk][g]
// 64x64 tile, BK=32, 4 waves in 2x2, each wave 32x32 (2x2 of 16x16x32 MFMA).
__global__ __launch_bounds__(256) void gemm_ih_k(
    const unsigned short* __restrict__ Xp, const unsigned short* __restrict__ Wb,
    const float* __restrict__ bias, float* __restrict__ ih) {
  const int mt = blockIdx.x, ntl = blockIdx.y, dk = blockIdx.z;
  const int kh = dk & 3;
  const int tid = threadIdx.x;
  const int L = tid & 63, w = tid >> 6;
  const int wm = w & 1, wn = w >> 1;
  const int quad = L >> 4, lo = L & 15;

  __shared__ unsigned short As[64 * 32];
  __shared__ unsigned short Bs[64 * 32];

  const unsigned short* Ab = Xp + (size_t)kh * 1048576 + (size_t)mt * 64 * 1024;
  const unsigned short* Bb = Wb + (size_t)dk * 2097152 + (size_t)ntl * 64 * 1024;
  const int srow = tid >> 2;          // 0..63
  const int schunk = (tid & 3) * 8;   // element offset within 32-wide row

  floatx4 acc[2][2] = {};

  for (int kc = 0; kc < 32; ++kc) {
    uint4 va = *(const uint4*)(Ab + (size_t)srow * 1024 + kc * 32 + schunk);
    uint4 vb = *(const uint4*)(Bb + (size_t)srow * 1024 + kc * 32 + schunk);
    __syncthreads();  // prior-iter LDS reads done
    *(uint4*)(As + srow * 32 + schunk) = va;
    *(uint4*)(Bs + srow * 32 + schunk) = vb;
    __syncthreads();
    short8 af[2], bfv[2];
#pragma unroll
    for (int mi = 0; mi < 2; ++mi)
      af[mi] = *(const short8*)(As + (wm * 32 + mi * 16 + lo) * 32 + quad * 8);
#pragma unroll
    for (int ni = 0; ni < 2; ++ni)
      bfv[ni] = *(const short8*)(Bs + (wn * 32 + ni * 16 + lo) * 32 + quad * 8);
#pragma unroll
    for (int mi = 0; mi < 2; ++mi)
#pragma unroll
      for (int ni = 0; ni < 2; ++ni)
        acc[mi][ni] = __builtin_amdgcn_mfma_f32_16x16x32_bf16(af[mi], bfv[ni], acc[mi][ni], 0, 0, 0);
  }

#pragma unroll
  for (int mi = 0; mi < 2; ++mi)
#pragma unroll
    for (int ni = 0; ni < 2; ++ni) {
      int g = ntl * 64 + wn * 32 + ni * 16 + lo;
      float bv = bias[dk * 2048 + g];
#pragma unroll
      for (int r = 0; r < 4; ++r) {
        int m = mt * 64 + wm * 32 + mi * 16 + quad * 4 + r;  // C/D: row=(L>>4)*4+r, col=L&15
        ih[((size_t)dk * 1024 + m) * 2048 + g] = acc[mi][ni][r] + bv;
      }
    }
}

// Persistent recurrence. grid=256: group = blockIdx&7 (d*4+k, XCD-swizzled),
// wg = blockIdx>>3 owns h-cols [wg*16, wg*16+16). Wave w = gate section (i,f,g,o).
__global__ __launch_bounds__(256) void lstm_rec_k(
    const float* __restrict__ ih, const unsigned short* __restrict__ whh,
    float* __restrict__ out, unsigned* __restrict__ cnt, unsigned short* __restrict__ state) {
  const int tid = threadIdx.x;
  const int L = tid & 63;
  const int w = tid >> 6;
  const int grp = blockIdx.x & 7;
  const int d = grp >> 2, kh = grp & 3;
  const int wg = blockIdx.x >> 3;
  const int j0 = wg * 16;
  const int quad = L >> 4, lo = L & 15;

  __shared__ unsigned short h_lds[16 * 520];  // rows 8..15 stay zero (M-pad); +8 col pad = 2-way banks
  __shared__ float gbuf[4][8][16];            // [section][b][jj]
  __shared__ float c_lds[128];                // [b][jj]

  for (int i = tid; i < 16 * 520; i += 256) h_lds[i] = 0;
  if (tid < 128) c_lds[tid] = 0.0f;

  // Whh slice -> register-resident B-fragments (one 16-col N-tile per wave).
  // B[k][n]: lane holds n = L&15 (gate row g = w*512 + j0 + lo), k = kk*32 + quad*8 + j.
  short8 bfrag[16];
  {
    const unsigned short* wb =
        whh + ((size_t)grp * 2048 + (size_t)(w * 512 + j0 + lo)) * 512 + quad * 8;
#pragma unroll
    for (int kk = 0; kk < 16; ++kk) bfrag[kk] = *(const short8*)(wb + kk * 32);
  }
  __syncthreads();

  unsigned* bar = cnt + grp * 64;  // 256B-spaced counters

  for (int s = 0; s < 128; ++s) {
    const int t = d ? (127 - s) : s;

    {  // stage h_prev [8][512] bf16 -> LDS (padded rows)
      const unsigned short* src = state + (size_t)(grp * 2 + (s & 1)) * 4096 + tid * 16;
      uint4 v0 = *(const uint4*)(src);
      uint4 v1 = *(const uint4*)(src + 8);
      unsigned short* dstl = h_lds + (tid >> 5) * 520 + (tid & 31) * 16;
      *(uint4*)(dstl) = v0;
      *(uint4*)(dstl + 8) = v1;
    }
    __syncthreads();

    // prefetch ih gates (hidden under MFMA)
    float ihv[4];
    const float* ihp = ih + ((size_t)grp * 1024 + (size_t)t * 8) * 2048 + (w * 512 + j0 + lo);
#pragma unroll
    for (int r = 0; r < 4; ++r) {
      int b = quad * 4 + r;
      ihv[r] = (b < 8) ? ihp[(size_t)b * 2048] : 0.0f;
    }

    floatx4 acc = {0.0f, 0.0f, 0.0f, 0.0f};
    {  // A[m][k]: m = L&15 (batch, rows 8..15 zero), k = kk*32 + quad*8 + j
      const unsigned short* ar = h_lds + lo * 520 + quad * 8;
#pragma unroll
      for (int kk = 0; kk < 16; ++kk) {
        short8 a = *(const short8*)(ar + kk * 32);
        acc = __builtin_amdgcn_mfma_f32_16x16x32_bf16(a, bfrag[kk], acc, 0, 0, 0);
      }
    }
#pragma unroll
    for (int r = 0; r < 4; ++r) {
      int b = quad * 4 + r;
      if (b < 8) gbuf[w][b][lo] = acc[r] + ihv[r];
    }
    __syncthreads();

    if (tid < 128) {  // pointwise LSTM cell for (b, jj)
      int b = tid >> 4, jj = tid & 15;
      float ig = gbuf[0][b][jj], fg = gbuf[1][b][jj];
      float gg = gbuf[2][b][jj], og = gbuf[3][b][jj];
      float c = c_lds[tid];
      float cn = sigm(fg) * c + sigm(ig) * tanh_f(gg);
      float h = sigm(og) * tanh_f(cn);
      c_lds[tid] = cn;
      int j = j0 + jj;
      // out[b][t][d*512 + j][kh]
      out[(((size_t)b * 128 + t) * 1024 + d * 512 + j) * 4 + kh] = h;
      state[(size_t)(grp * 2 + ((s + 1) & 1)) * 4096 + b * 512 + j] = f2bf(h);
    }

    if (s < 127) {  // per-group barrier: monotonic count, release/acquire agent scope
      __threadfence();
      __syncthreads();
      if (tid == 0) {
        __hip_atomic_fetch_add(bar, 1u, __ATOMIC_RELEASE, __HIP_MEMORY_SCOPE_AGENT);
        unsigned tgt = 32u * (unsigned)(s + 1);
        while (__hip_atomic_load(bar, __ATOMIC_ACQUIRE, __HIP_MEMORY_SCOPE_AGENT) < tgt)
          __builtin_amdgcn_s_sleep(2);
      }
      __syncthreads();
    }
  }
}

extern "C" void kernel_launch(void* const* d_in, const int* in_sizes, int n_in,
                              void* d_out, int out_size, void* d_ws, size_t ws_size,
                              hipStream_t stream) {
  (void)in_sizes; (void)n_in; (void)out_size; (void)ws_size;
  const float* x     = (const float*)d_in[0];
  const float* Wih_f = (const float*)d_in[1];
  const float* Whh_f = (const float*)d_in[2];
  const float* bih_f = (const float*)d_in[3];
  const float* bhh_f = (const float*)d_in[4];
  const float* Wih_b = (const float*)d_in[5];
  const float* Whh_b = (const float*)d_in[6];
  const float* bih_b = (const float*)d_in[7];
  const float* bhh_b = (const float*)d_in[8];
  float* out = (float*)d_out;
  char* ws = (char*)d_ws;

  unsigned* cnt        = (unsigned*)(ws);                      // 4 KB
  unsigned short* st   = (unsigned short*)(ws + 4096);         // 128 KB h-state (2 parities)
  float* bias          = (float*)(ws + (256u << 10));          // 64 KB
  float* ihg           = (float*)(ws + (1ull << 20));          // 64 MB fp32 ih gates
  unsigned short* Xp   = (unsigned short*)(ws + (65ull << 20)); // 8 MB
  unsigned short* Wihb = (unsigned short*)(ws + (73ull << 20)); // 32 MB
  unsigned short* Whhb = (unsigned short*)(ws + (65ull << 20)); // 16 MB, reuses Xp/Wih after GEMM

  hipMemsetAsync(ws, 0, 4096 + 131072, stream);  // counters + h state
  pack_x_k<<<4096, 256, 0, stream>>>(x, Xp);
  cast_bf_k<<<8192, 256, 0, stream>>>(Wih_f, Wihb, 2097152);
  cast_bf_k<<<8192, 256, 0, stream>>>(Wih_b, Wihb + 8388608, 2097152);
  bias_k<<<64, 256, 0, stream>>>(bih_f, bhh_f, bih_b, bhh_b, bias);
  gemm_ih_k<<<dim3(16, 32, 8), 256, 0, stream>>>(Xp, Wihb, bias, ihg);
  cast_bf_k<<<4096, 256, 0, stream>>>(Whh_f, Whhb, 1048576);
  cast_bf_k<<<4096, 256, 0, stream>>>(Whh_b, Whhb + 4194304, 1048576);
  lstm_rec_k<<<256, 256, 0, stream>>>(ihg, Whhb, out, cnt, st);
}

// Round 2
// 931.325 us; speedup vs baseline: 3.8101x; 3.8101x over previous
//
#include <hip/hip_runtime.h>
#include <stdint.h>

// Multi_LSTMs: bidirectional 4-head LSTM, BS=8 NT=128 CH=1024 H=512 G=2048.
//   pack x + weights to bf16 -> MFMA GEMM for input-to-hidden gates (fp32 out)
//   -> persistent recurrence kernel: 8 groups (dir,head) x 32 WGs; Whh slice
//      register-resident as MFMA B-frags.
// R1 lesson: NO agent-scope fences/acquire in the step loop (buffer_wbl2 /
// buffer_inv storm = 26 us/step). All cross-WG data moves via RELAXED
// agent-scope atomics (sc1 -> served at LLC, no cache maintenance); ordering
// store->counter via wave-level s_waitcnt vmcnt(0) within wave 0.

typedef __attribute__((ext_vector_type(8))) short short8;
typedef __attribute__((ext_vector_type(4))) float floatx4;
typedef unsigned long long ull;

__device__ __forceinline__ unsigned short f2bf(float f) {
  unsigned u = __float_as_uint(f);
  u = (u + 0x7fffu + ((u >> 16) & 1u)) >> 16;  // RNE
  return (unsigned short)u;
}
__device__ __forceinline__ float sigm(float x) { return 1.0f / (1.0f + __expf(-x)); }
__device__ __forceinline__ float tanh_f(float x) {
  float ax = fabsf(x);
  float e = __expf(-2.0f * ax);
  float t = (1.0f - e) / (1.0f + e);
  return x < 0.0f ? -t : t;
}

// x[8][128][1024][4] f32 -> Xp[4][1024][1024] bf16, row m = t*8+b
__global__ void pack_x_k(const float* __restrict__ x, unsigned short* __restrict__ Xp) {
  int g = blockIdx.x * 256 + threadIdx.x;  // m*1024 + c
  int m = g >> 10, c = g & 1023;
  int t = m >> 3, b = m & 7;
  float4 v = *(const float4*)(x + ((size_t)((b * 128 + t) * 1024 + c)) * 4);
  Xp[g]           = f2bf(v.x);
  Xp[1048576 + g] = f2bf(v.y);
  Xp[2097152 + g] = f2bf(v.z);
  Xp[3145728 + g] = f2bf(v.w);
}

__global__ void cast_bf_k(const float* __restrict__ src, unsigned short* __restrict__ dst, int n4) {
  int i = blockIdx.x * 256 + threadIdx.x;
  if (i >= n4) return;
  float4 v = ((const float4*)src)[i];
  ushort4 o;
  o.x = f2bf(v.x); o.y = f2bf(v.y); o.z = f2bf(v.z); o.w = f2bf(v.w);
  ((ushort4*)dst)[i] = o;
}

__global__ void bias_k(const float* __restrict__ bihf, const float* __restrict__ bhhf,
                       const float* __restrict__ bihb, const float* __restrict__ bhhb,
                       float* __restrict__ bias) {
  int i = blockIdx.x * 256 + threadIdx.x;  // < 16384
  int dk = i >> 11, g = i & 2047, kk = dk & 3;
  const float* a = (dk < 4) ? bihf : bihb;
  const float* b = (dk < 4) ? bhhf : bhhb;
  bias[i] = a[kk * 2048 + g] + b[kk * 2048 + g];
}

// ih[dk][m][g] = sum_c Xp[kh][m][c] * Wb[dk][g][c] + bias[dk][g]
__global__ __launch_bounds__(256) void gemm_ih_k(
    const unsigned short* __restrict__ Xp, const unsigned short* __restrict__ Wb,
    const float* __restrict__ bias, float* __restrict__ ih) {
  const int mt = blockIdx.x, ntl = blockIdx.y, dk = blockIdx.z;
  const int kh = dk & 3;
  const int tid = threadIdx.x;
  const int L = tid & 63, w = tid >> 6;
  const int wm = w & 1, wn = w >> 1;
  const int quad = L >> 4, lo = L & 15;

  __shared__ unsigned short As[64 * 32];
  __shared__ unsigned short Bs[64 * 32];

  const unsigned short* Ab = Xp + (size_t)kh * 1048576 + (size_t)mt * 64 * 1024;
  const unsigned short* Bb = Wb + (size_t)dk * 2097152 + (size_t)ntl * 64 * 1024;
  const int srow = tid >> 2;
  const int schunk = (tid & 3) * 8;

  floatx4 acc[2][2] = {};

  for (int kc = 0; kc < 32; ++kc) {
    uint4 va = *(const uint4*)(Ab + (size_t)srow * 1024 + kc * 32 + schunk);
    uint4 vb = *(const uint4*)(Bb + (size_t)srow * 1024 + kc * 32 + schunk);
    __syncthreads();
    *(uint4*)(As + srow * 32 + schunk) = va;
    *(uint4*)(Bs + srow * 32 + schunk) = vb;
    __syncthreads();
    short8 af[2], bfv[2];
#pragma unroll
    for (int mi = 0; mi < 2; ++mi)
      af[mi] = *(const short8*)(As + (wm * 32 + mi * 16 + lo) * 32 + quad * 8);
#pragma unroll
    for (int ni = 0; ni < 2; ++ni)
      bfv[ni] = *(const short8*)(Bs + (wn * 32 + ni * 16 + lo) * 32 + quad * 8);
#pragma unroll
    for (int mi = 0; mi < 2; ++mi)
#pragma unroll
      for (int ni = 0; ni < 2; ++ni)
        acc[mi][ni] = __builtin_amdgcn_mfma_f32_16x16x32_bf16(af[mi], bfv[ni], acc[mi][ni], 0, 0, 0);
  }

#pragma unroll
  for (int mi = 0; mi < 2; ++mi)
#pragma unroll
    for (int ni = 0; ni < 2; ++ni) {
      int g = ntl * 64 + wn * 32 + ni * 16 + lo;
      float bv = bias[dk * 2048 + g];
#pragma unroll
      for (int r = 0; r < 4; ++r) {
        int m = mt * 64 + wm * 32 + mi * 16 + quad * 4 + r;
        ih[((size_t)dk * 1024 + m) * 2048 + g] = acc[mi][ni][r] + bv;
      }
    }
}

// Persistent recurrence. grid=256: group = blockIdx&7, wg = blockIdx>>3 owns
// h-cols [wg*16, wg*16+16). Wave w = gate section (i,f,g,o).
__global__ __launch_bounds__(256) void lstm_rec_k(
    const float* __restrict__ ih, const unsigned short* __restrict__ whh,
    float* __restrict__ out, unsigned* __restrict__ cnt, ull* __restrict__ state) {
  const int tid = threadIdx.x;
  const int L = tid & 63;
  const int w = tid >> 6;
  const int grp = blockIdx.x & 7;
  const int d = grp >> 2, kh = grp & 3;
  const int wg = blockIdx.x >> 3;
  const int j0 = wg * 16;
  const int quad = L >> 4, lo = L & 15;

  __shared__ unsigned short h_lds[16 * 520];  // rows 8..15 stay zero (M-pad)
  __shared__ float gbuf[4][8][16];            // [section][b][jj]

  for (int i = tid; i < 16 * 520; i += 256) h_lds[i] = 0;

  // Whh slice -> register-resident B-fragments (16-col N-tile per wave).
  short8 bfrag[16];
  {
    const unsigned short* wb =
        whh + ((size_t)grp * 2048 + (size_t)(w * 512 + j0 + lo)) * 512 + quad * 8;
#pragma unroll
    for (int kk = 0; kk < 16; ++kk) bfrag[kk] = *(const short8*)(wb + kk * 32);
  }
  __syncthreads();

  unsigned* bar = cnt + grp * 64;  // 256B-spaced counters

  // pointwise-cell c-state lives in registers of wave0 lanes 0..31 (4 cells each)
  float creg[4] = {0.0f, 0.0f, 0.0f, 0.0f};

  // prefetch ih gates for s=0
  float ihv[4];
  {
    int t0 = d ? 127 : 0;
    const float* ihp = ih + ((size_t)grp * 1024 + (size_t)t0 * 8) * 2048 + (w * 512 + j0 + lo);
#pragma unroll
    for (int r = 0; r < 4; ++r) {
      int b = quad * 4 + r;
      ihv[r] = (b < 8) ? ihp[(size_t)b * 2048] : 0.0f;
    }
  }

  const int srow = tid >> 5;            // batch row 0..7
  const int scol = (tid & 31) * 16;     // h-column base within row

  for (int s = 0; s < 128; ++s) {
    const int t = d ? (127 - s) : s;

    {  // stage h_prev [8][512] bf16 via relaxed agent-scope 8B atomic loads
      const ull* src = state + (size_t)(grp * 2 + (s & 1)) * 1024 + tid * 4;
      ull v[4];
#pragma unroll
      for (int q = 0; q < 4; ++q)
        v[q] = __hip_atomic_load(src + q, __ATOMIC_RELAXED, __HIP_MEMORY_SCOPE_AGENT);
#pragma unroll
      for (int q = 0; q < 4; ++q)
        *(ull*)(h_lds + srow * 520 + scol + 4 * q) = v[q];
    }
    __syncthreads();

    floatx4 acc = {0.0f, 0.0f, 0.0f, 0.0f};
    {  // A[m][k]: m = L&15 (batch, rows 8..15 zero), k = kk*32 + quad*8 + j
      const unsigned short* ar = h_lds + lo * 520 + quad * 8;
#pragma unroll
      for (int kk = 0; kk < 16; ++kk) {
        short8 a = *(const short8*)(ar + kk * 32);
        acc = __builtin_amdgcn_mfma_f32_16x16x32_bf16(a, bfrag[kk], acc, 0, 0, 0);
      }
    }
#pragma unroll
    for (int r = 0; r < 4; ++r) {
      int b = quad * 4 + r;
      if (b < 8) gbuf[w][b][lo] = acc[r] + ihv[r];
    }
    __syncthreads();

    // pointwise LSTM cell: wave0 lanes 0..31, 4 cells each (b, j0+4q..+3)
    if (tid < 32) {
      int b = tid >> 2, q = tid & 3;
      float hh[4];
#pragma unroll
      for (int u = 0; u < 4; ++u) {
        int jj = 4 * q + u;
        float ig = gbuf[0][b][jj], fg = gbuf[1][b][jj];
        float gg = gbuf[2][b][jj], og = gbuf[3][b][jj];
        float cn = sigm(fg) * creg[u] + sigm(ig) * tanh_f(gg);
        creg[u] = cn;
        float h = sigm(og) * tanh_f(cn);
        hh[u] = h;
        int j = j0 + jj;
        out[(((size_t)b * 128 + t) * 1024 + d * 512 + j) * 4 + kh] = h;  // plain store
      }
      if (s < 127) {
        ull wv = (ull)f2bf(hh[0]) | ((ull)f2bf(hh[1]) << 16) |
                 ((ull)f2bf(hh[2]) << 32) | ((ull)f2bf(hh[3]) << 48);
        ull* dst = state + (size_t)(grp * 2 + ((s + 1) & 1)) * 1024 + b * 128 + wg * 4 + q;
        __hip_atomic_store(dst, wv, __ATOMIC_RELAXED, __HIP_MEMORY_SCOPE_AGENT);
      }
    }

    if (s < 127) {
      // wave0: drain state stores (and out stores) before signaling
      if (w == 0) __builtin_amdgcn_s_waitcnt(0x0F70);  // vmcnt(0), lgkm/exp free

      // prefetch ih for s+1 while waiting on the barrier
      {
        int tn = d ? (126 - s) : (s + 1);
        const float* ihp = ih + ((size_t)grp * 1024 + (size_t)tn * 8) * 2048 + (w * 512 + j0 + lo);
#pragma unroll
        for (int r = 0; r < 4; ++r) {
          int b = quad * 4 + r;
          ihv[r] = (b < 8) ? ihp[(size_t)b * 2048] : 0.0f;
        }
      }

      if (tid == 0)
        __hip_atomic_fetch_add(bar, 1u, __ATOMIC_RELAXED, __HIP_MEMORY_SCOPE_AGENT);
      // per-wave poll: lane 0 of each wave spins on the group counter
      if (L == 0) {
        unsigned tgt = 32u * (unsigned)(s + 1);
        while (__hip_atomic_load(bar, __ATOMIC_RELAXED, __HIP_MEMORY_SCOPE_AGENT) < tgt)
          __builtin_amdgcn_s_sleep(1);
      }
      // wave reconverges here; stage loads of s+1 are exec-masked until then
    }
  }
}

extern "C" void kernel_launch(void* const* d_in, const int* in_sizes, int n_in,
                              void* d_out, int out_size, void* d_ws, size_t ws_size,
                              hipStream_t stream) {
  (void)in_sizes; (void)n_in; (void)out_size; (void)ws_size;
  const float* x     = (const float*)d_in[0];
  const float* Wih_f = (const float*)d_in[1];
  const float* Whh_f = (const float*)d_in[2];
  const float* bih_f = (const float*)d_in[3];
  const float* bhh_f = (const float*)d_in[4];
  const float* Wih_b = (const float*)d_in[5];
  const float* Whh_b = (const float*)d_in[6];
  const float* bih_b = (const float*)d_in[7];
  const float* bhh_b = (const float*)d_in[8];
  float* out = (float*)d_out;
  char* ws = (char*)d_ws;

  unsigned* cnt        = (unsigned*)(ws);                       // 4 KB
  ull* st              = (ull*)(ws + 4096);                     // 128 KB h-state (2 parities)
  float* bias          = (float*)(ws + (256u << 10));           // 64 KB
  float* ihg           = (float*)(ws + (1ull << 20));           // 64 MB fp32 ih gates
  unsigned short* Xp   = (unsigned short*)(ws + (65ull << 20)); // 8 MB
  unsigned short* Wihb = (unsigned short*)(ws + (73ull << 20)); // 32 MB
  unsigned short* Whhb = (unsigned short*)(ws + (65ull << 20)); // 16 MB, reuses Xp/Wih after GEMM

  hipMemsetAsync(ws, 0, 4096 + 131072, stream);  // counters + h state
  pack_x_k<<<4096, 256, 0, stream>>>(x, Xp);
  cast_bf_k<<<8192, 256, 0, stream>>>(Wih_f, Wihb, 2097152);
  cast_bf_k<<<8192, 256, 0, stream>>>(Wih_b, Wihb + 8388608, 2097152);
  bias_k<<<64, 256, 0, stream>>>(bih_f, bhh_f, bih_b, bhh_b, bias);
  gemm_ih_k<<<dim3(16, 32, 8), 256, 0, stream>>>(Xp, Wihb, bias, ihg);
  cast_bf_k<<<4096, 256, 0, stream>>>(Whh_f, Whhb, 1048576);
  cast_bf_k<<<4096, 256, 0, stream>>>(Whh_b, Whhb + 4194304, 1048576);
  lstm_rec_k<<<256, 256, 0, stream>>>(ihg, Whhb, out, cnt, st);
}

// Round 3
// 611.935 us; speedup vs baseline: 5.7987x; 1.5219x over previous
//
#include <hip/hip_runtime.h>
#include <stdint.h>

// Multi_LSTMs: bidirectional 4-head LSTM, BS=8 NT=128 CH=1024 H=512 G=2048.
//   pack x + weights to bf16 -> MFMA GEMM for input-to-hidden gates (fp32 out)
//   -> persistent recurrence kernel: 8 groups (dir,head) x 16 WGs; Whh slice
//      register-resident as MFMA B-frags (128 VGPR/lane).
// R1 lesson: NO agent-scope fences/acquire in step loop (buffer_wbl2/inv storm).
// R2 lesson: same-address fetch_add barrier + 128 pollers on one line is slow;
//   R3 uses per-producer tag array (no RMW), 16 producers, shfl-packed state.

typedef __attribute__((ext_vector_type(8))) short short8;
typedef __attribute__((ext_vector_type(4))) float floatx4;
typedef unsigned long long ull;

__device__ __forceinline__ unsigned short f2bf(float f) {
  unsigned u = __float_as_uint(f);
  u = (u + 0x7fffu + ((u >> 16) & 1u)) >> 16;  // RNE
  return (unsigned short)u;
}
__device__ __forceinline__ float sigm(float x) { return 1.0f / (1.0f + __expf(-x)); }
__device__ __forceinline__ float tanh_f(float x) {
  float ax = fabsf(x);
  float e = __expf(-2.0f * ax);
  float t = (1.0f - e) / (1.0f + e);
  return x < 0.0f ? -t : t;
}

// x[8][128][1024][4] f32 -> Xp[4][1024][1024] bf16, row m = t*8+b
__global__ void pack_x_k(const float* __restrict__ x, unsigned short* __restrict__ Xp) {
  int g = blockIdx.x * 256 + threadIdx.x;
  int m = g >> 10, c = g & 1023;
  int t = m >> 3, b = m & 7;
  float4 v = *(const float4*)(x + ((size_t)((b * 128 + t) * 1024 + c)) * 4);
  Xp[g]           = f2bf(v.x);
  Xp[1048576 + g] = f2bf(v.y);
  Xp[2097152 + g] = f2bf(v.z);
  Xp[3145728 + g] = f2bf(v.w);
}

__global__ void cast_bf_k(const float* __restrict__ src, unsigned short* __restrict__ dst, int n4) {
  int i = blockIdx.x * 256 + threadIdx.x;
  if (i >= n4) return;
  float4 v = ((const float4*)src)[i];
  ushort4 o;
  o.x = f2bf(v.x); o.y = f2bf(v.y); o.z = f2bf(v.z); o.w = f2bf(v.w);
  ((ushort4*)dst)[i] = o;
}

__global__ void bias_k(const float* __restrict__ bihf, const float* __restrict__ bhhf,
                       const float* __restrict__ bihb, const float* __restrict__ bhhb,
                       float* __restrict__ bias) {
  int i = blockIdx.x * 256 + threadIdx.x;
  int dk = i >> 11, g = i & 2047, kk = dk & 3;
  const float* a = (dk < 4) ? bihf : bihb;
  const float* b = (dk < 4) ? bhhf : bhhb;
  bias[i] = a[kk * 2048 + g] + b[kk * 2048 + g];
}

// ih[dk][m][g] = sum_c Xp[kh][m][c] * Wb[dk][g][c] + bias[dk][g]
__global__ __launch_bounds__(256) void gemm_ih_k(
    const unsigned short* __restrict__ Xp, const unsigned short* __restrict__ Wb,
    const float* __restrict__ bias, float* __restrict__ ih) {
  const int mt = blockIdx.x, ntl = blockIdx.y, dk = blockIdx.z;
  const int kh = dk & 3;
  const int tid = threadIdx.x;
  const int L = tid & 63, w = tid >> 6;
  const int wm = w & 1, wn = w >> 1;
  const int quad = L >> 4, lo = L & 15;

  __shared__ unsigned short As[64 * 32];
  __shared__ unsigned short Bs[64 * 32];

  const unsigned short* Ab = Xp + (size_t)kh * 1048576 + (size_t)mt * 64 * 1024;
  const unsigned short* Bb = Wb + (size_t)dk * 2097152 + (size_t)ntl * 64 * 1024;
  const int srow = tid >> 2;
  const int schunk = (tid & 3) * 8;

  floatx4 acc[2][2] = {};

  for (int kc = 0; kc < 32; ++kc) {
    uint4 va = *(const uint4*)(Ab + (size_t)srow * 1024 + kc * 32 + schunk);
    uint4 vb = *(const uint4*)(Bb + (size_t)srow * 1024 + kc * 32 + schunk);
    __syncthreads();
    *(uint4*)(As + srow * 32 + schunk) = va;
    *(uint4*)(Bs + srow * 32 + schunk) = vb;
    __syncthreads();
    short8 af[2], bfv[2];
#pragma unroll
    for (int mi = 0; mi < 2; ++mi)
      af[mi] = *(const short8*)(As + (wm * 32 + mi * 16 + lo) * 32 + quad * 8);
#pragma unroll
    for (int ni = 0; ni < 2; ++ni)
      bfv[ni] = *(const short8*)(Bs + (wn * 32 + ni * 16 + lo) * 32 + quad * 8);
#pragma unroll
    for (int mi = 0; mi < 2; ++mi)
#pragma unroll
      for (int ni = 0; ni < 2; ++ni)
        acc[mi][ni] = __builtin_amdgcn_mfma_f32_16x16x32_bf16(af[mi], bfv[ni], acc[mi][ni], 0, 0, 0);
  }

#pragma unroll
  for (int mi = 0; mi < 2; ++mi)
#pragma unroll
    for (int ni = 0; ni < 2; ++ni) {
      int g = ntl * 64 + wn * 32 + ni * 16 + lo;
      float bv = bias[dk * 2048 + g];
#pragma unroll
      for (int r = 0; r < 4; ++r) {
        int m = mt * 64 + wm * 32 + mi * 16 + quad * 4 + r;
        ih[((size_t)dk * 1024 + m) * 2048 + g] = acc[mi][ni][r] + bv;
      }
    }
}

// Persistent recurrence. grid=128: group = blockIdx&7, wg = blockIdx>>3 owns
// h-cols [wg*32, wg*32+32). Wave w = gate section (i,f,g,o), 2 N-tiles each.
__global__ __launch_bounds__(256) void lstm_rec_k(
    const float* __restrict__ ih, const unsigned short* __restrict__ whh,
    float* __restrict__ out, unsigned* __restrict__ tags, ull* __restrict__ state) {
  const int tid = threadIdx.x;
  const int L = tid & 63;
  const int w = tid >> 6;
  const int grp = blockIdx.x & 7;
  const int d = grp >> 2, kh = grp & 3;
  const int wg = blockIdx.x >> 3;
  const int j0 = wg * 32;
  const int quad = L >> 4, lo = L & 15;

  __shared__ unsigned short h_lds[16 * 520];  // rows 8..15 stay zero (M-pad)
  __shared__ float gbuf[4][8][32];            // [gate][b][jj]

  for (int i = tid; i < 16 * 520; i += 256) h_lds[i] = 0;

  // Whh slice -> register B-frags: wave w, gate rows g = w*512 + j0 + ni*16 + lo
  short8 bfrag[2][16];
  {
#pragma unroll
    for (int ni = 0; ni < 2; ++ni) {
      const unsigned short* wb =
          whh + ((size_t)grp * 2048 + (size_t)(w * 512 + j0 + ni * 16 + lo)) * 512 + quad * 8;
#pragma unroll
      for (int kk = 0; kk < 16; ++kk) bfrag[ni][kk] = *(const short8*)(wb + kk * 32);
    }
  }
  __syncthreads();

  unsigned* mytags = tags + grp * 16;  // one 64B line per group

  // pointwise cell state: 1 cell per thread (b = tid>>5, jj = tid&31)
  const int pb = tid >> 5, pjj = tid & 31;
  float creg = 0.0f;

  // prefetch ih gates for s=0: 2 N-tiles x 4 rows per lane
  float ihv[2][4];
  {
    int t0 = d ? 127 : 0;
#pragma unroll
    for (int ni = 0; ni < 2; ++ni) {
      const float* ihp =
          ih + ((size_t)grp * 1024 + (size_t)t0 * 8) * 2048 + (w * 512 + j0 + ni * 16 + lo);
#pragma unroll
      for (int r = 0; r < 4; ++r) {
        int b = quad * 4 + r;
        ihv[ni][r] = (b < 8) ? ihp[(size_t)b * 2048] : 0.0f;
      }
    }
  }

  const int srow = tid >> 5;         // batch row 0..7
  const int scol = (tid & 31) * 16;  // h-col base within row (elements)

  for (int s = 0; s < 128; ++s) {
    const int t = d ? (127 - s) : s;

    {  // stage h_prev [8][512] bf16 via relaxed agent-scope 8B loads
      const ull* src = state + (size_t)(grp * 2 + (s & 1)) * 1024 + tid * 4;
      ull v[4];
#pragma unroll
      for (int q = 0; q < 4; ++q)
        v[q] = __hip_atomic_load(src + q, __ATOMIC_RELAXED, __HIP_MEMORY_SCOPE_AGENT);
#pragma unroll
      for (int q = 0; q < 4; ++q)
        *(ull*)(h_lds + srow * 520 + scol + 4 * q) = v[q];
    }
    __syncthreads();

    floatx4 acc[2] = {};
    {  // A[m][k]: m = L&15 (batch, rows 8..15 zero), k = kk*32 + quad*8 + j
      const unsigned short* ar = h_lds + lo * 520 + quad * 8;
#pragma unroll
      for (int kk = 0; kk < 16; ++kk) {
        short8 a = *(const short8*)(ar + kk * 32);
#pragma unroll
        for (int ni = 0; ni < 2; ++ni)
          acc[ni] = __builtin_amdgcn_mfma_f32_16x16x32_bf16(a, bfrag[ni][kk], acc[ni], 0, 0, 0);
      }
    }
#pragma unroll
    for (int ni = 0; ni < 2; ++ni)
#pragma unroll
      for (int r = 0; r < 4; ++r) {
        int b = quad * 4 + r;
        if (b < 8) gbuf[w][b][ni * 16 + lo] = acc[ni][r] + ihv[ni][r];
      }
    __syncthreads();

    // pointwise LSTM cell: one (b, jj) per thread
    {
      float ig = gbuf[0][pb][pjj], fg = gbuf[1][pb][pjj];
      float gg = gbuf[2][pb][pjj], og = gbuf[3][pb][pjj];
      float cn = sigm(fg) * creg + sigm(ig) * tanh_f(gg);
      creg = cn;
      float h = sigm(og) * tanh_f(cn);

      if (s < 127) {  // publish h: shfl-pack 4 lanes -> one 8B relaxed store
        unsigned hs = f2bf(h);
        int base = L & ~3;
        unsigned v0 = __shfl(hs, base + 0);
        unsigned v1 = __shfl(hs, base + 1);
        unsigned v2 = __shfl(hs, base + 2);
        unsigned v3 = __shfl(hs, base + 3);
        if ((L & 3) == 0) {
          ull wv = (ull)v0 | ((ull)v1 << 16) | ((ull)v2 << 32) | ((ull)v3 << 48);
          ull* dst = state + (size_t)(grp * 2 + ((s + 1) & 1)) * 1024 + pb * 128 + ((j0 + pjj) >> 2);
          __hip_atomic_store(dst, wv, __ATOMIC_RELAXED, __HIP_MEMORY_SCOPE_AGENT);
        }
      }
      out[(((size_t)pb * 128 + t) * 1024 + d * 512 + j0 + pjj) * 4 + kh] = h;
    }

    if (s < 127) {
      __builtin_amdgcn_s_waitcnt(0x0F70);  // per-wave: drain state (+out) stores
      __syncthreads();                     // all waves drained
      if (tid == 0)  // publish tag: plain slot, no RMW
        __hip_atomic_store(mytags + wg, (unsigned)(s + 1), __ATOMIC_RELAXED,
                           __HIP_MEMORY_SCOPE_AGENT);

      // prefetch ih for s+1 (overlaps the poll)
      {
        int tn = d ? (126 - s) : (s + 1);
#pragma unroll
        for (int ni = 0; ni < 2; ++ni) {
          const float* ihp =
              ih + ((size_t)grp * 1024 + (size_t)tn * 8) * 2048 + (w * 512 + j0 + ni * 16 + lo);
#pragma unroll
          for (int r = 0; r < 4; ++r) {
            int b = quad * 4 + r;
            ihv[ni][r] = (b < 8) ? ihp[(size_t)b * 2048] : 0.0f;
          }
        }
      }

      // per-wave poll: lanes 0..15 load the 16-tag line, wave-wide check
      unsigned tgt = (unsigned)(s + 1);
      for (;;) {
        unsigned v = tgt;
        if (L < 16)
          v = __hip_atomic_load(mytags + L, __ATOMIC_RELAXED, __HIP_MEMORY_SCOPE_AGENT);
        if (__all(v >= tgt)) break;
      }
    }
  }
}

extern "C" void kernel_launch(void* const* d_in, const int* in_sizes, int n_in,
                              void* d_out, int out_size, void* d_ws, size_t ws_size,
                              hipStream_t stream) {
  (void)in_sizes; (void)n_in; (void)out_size; (void)ws_size;
  const float* x     = (const float*)d_in[0];
  const float* Wih_f = (const float*)d_in[1];
  const float* Whh_f = (const float*)d_in[2];
  const float* bih_f = (const float*)d_in[3];
  const float* bhh_f = (const float*)d_in[4];
  const float* Wih_b = (const float*)d_in[5];
  const float* Whh_b = (const float*)d_in[6];
  const float* bih_b = (const float*)d_in[7];
  const float* bhh_b = (const float*)d_in[8];
  float* out = (float*)d_out;
  char* ws = (char*)d_ws;

  unsigned* tags       = (unsigned*)(ws);                       // 4 KB (8 grp x 16 tags)
  ull* st              = (ull*)(ws + 4096);                     // 128 KB h-state (2 parities)
  float* bias          = (float*)(ws + (256u << 10));           // 64 KB
  float* ihg           = (float*)(ws + (1ull << 20));           // 64 MB fp32 ih gates
  unsigned short* Xp   = (unsigned short*)(ws + (65ull << 20)); // 8 MB
  unsigned short* Wihb = (unsigned short*)(ws + (73ull << 20)); // 32 MB
  unsigned short* Whhb = (unsigned short*)(ws + (65ull << 20)); // 16 MB, reuses Xp/Wih after GEMM

  hipMemsetAsync(ws, 0, 4096 + 131072, stream);  // tags + h state
  pack_x_k<<<4096, 256, 0, stream>>>(x, Xp);
  cast_bf_k<<<8192, 256, 0, stream>>>(Wih_f, Wihb, 2097152);
  cast_bf_k<<<8192, 256, 0, stream>>>(Wih_b, Wihb + 8388608, 2097152);
  bias_k<<<64, 256, 0, stream>>>(bih_f, bhh_f, bih_b, bhh_b, bias);
  gemm_ih_k<<<dim3(16, 32, 8), 256, 0, stream>>>(Xp, Wihb, bias, ihg);
  cast_bf_k<<<4096, 256, 0, stream>>>(Whh_f, Whhb, 1048576);
  cast_bf_k<<<4096, 256, 0, stream>>>(Whh_b, Whhb + 4194304, 1048576);
  lstm_rec_k<<<128, 256, 0, stream>>>(ihg, Whhb, out, tags, st);
}

// Round 4
// 496.264 us; speedup vs baseline: 7.1502x; 1.2331x over previous
//
#include <hip/hip_runtime.h>
#include <stdint.h>

// Multi_LSTMs: bidirectional 4-head LSTM, BS=8 NT=128 CH=1024 H=512 G=2048.
//   pack x + weights to bf16 -> m97-style MFMA GEMM (128x128 tile,
//   global_load_lds) for input-to-hidden gates -> persistent recurrence:
//   8 groups (dir,head) x 16 WGs; Whh register-resident as MFMA B-frags.
// R1: NO agent-scope fences/acquire in step loop (buffer_wbl2/inv storm).
// R2: no same-address RMW barrier (line-lock serialization).
// R3->R4: no data->flag ordering at all: consumers poll the state words
//   themselves against a bf16-NaN poison (h is never NaN). Removes the
//   vmcnt(0) drain + tag-visibility RT from the serial chain.

typedef __attribute__((ext_vector_type(8))) short short8;
typedef __attribute__((ext_vector_type(4))) float floatx4;
typedef unsigned long long ull;

#define POISON 0x7FC07FC07FC07FC0ull  // 4 x bf16 NaN

#define GLOAD_LDS16(g, l)                                        \
  __builtin_amdgcn_global_load_lds(                              \
      (const __attribute__((address_space(1))) void*)(g),        \
      (__attribute__((address_space(3))) void*)(l), 16, 0, 0)

__device__ __forceinline__ unsigned short f2bf(float f) {
  unsigned u = __float_as_uint(f);
  u = (u + 0x7fffu + ((u >> 16) & 1u)) >> 16;  // RNE
  return (unsigned short)u;
}
__device__ __forceinline__ float sigm(float x) { return 1.0f / (1.0f + __expf(-x)); }
__device__ __forceinline__ float tanh_f(float x) {
  float ax = fabsf(x);
  float e = __expf(-2.0f * ax);
  float t = (1.0f - e) / (1.0f + e);
  return x < 0.0f ? -t : t;
}

// x[8][128][1024][4] f32 -> Xp[4][1024][1024] bf16, row m = t*8+b
__global__ void pack_x_k(const float* __restrict__ x, unsigned short* __restrict__ Xp) {
  int g = blockIdx.x * 256 + threadIdx.x;
  int m = g >> 10, c = g & 1023;
  int t = m >> 3, b = m & 7;
  float4 v = *(const float4*)(x + ((size_t)((b * 128 + t) * 1024 + c)) * 4);
  Xp[g]           = f2bf(v.x);
  Xp[1048576 + g] = f2bf(v.y);
  Xp[2097152 + g] = f2bf(v.z);
  Xp[3145728 + g] = f2bf(v.w);
}

__global__ void cast_bf_k(const float* __restrict__ src, unsigned short* __restrict__ dst, int n4) {
  int i = blockIdx.x * 256 + threadIdx.x;
  if (i >= n4) return;
  float4 v = ((const float4*)src)[i];
  ushort4 o;
  o.x = f2bf(v.x); o.y = f2bf(v.y); o.z = f2bf(v.z); o.w = f2bf(v.w);
  ((ushort4*)dst)[i] = o;
}

__global__ void bias_k(const float* __restrict__ bihf, const float* __restrict__ bhhf,
                       const float* __restrict__ bihb, const float* __restrict__ bhhb,
                       float* __restrict__ bias) {
  int i = blockIdx.x * 256 + threadIdx.x;
  int dk = i >> 11, g = i & 2047, kk = dk & 3;
  const float* a = (dk < 4) ? bihf : bihb;
  const float* b = (dk < 4) ? bhhf : bhhb;
  bias[i] = a[kk * 2048 + g] + b[kk * 2048 + g];
}

__global__ void fill_poison_k(ull* __restrict__ p) {
  p[(size_t)blockIdx.x * 256 + threadIdx.x] = POISON;
}

// ih[dk][m][g] = sum_c Xp[kh][m][c] * Wb[dk][g][c] + bias[dk][g]
// m97 structure: 128x128 tile, BK=32, global_load_lds(16B), 4 waves 2x2,
// each wave 64x64 = 4x4 accs of 16x16x32.
__global__ __launch_bounds__(256) void gemm_ih_k(
    const unsigned short* __restrict__ Xp, const unsigned short* __restrict__ Wb,
    const float* __restrict__ bias, float* __restrict__ ih) {
  const int mt = blockIdx.x, ntl = blockIdx.y, dk = blockIdx.z;
  const int kh = dk & 3;
  const int tid = threadIdx.x;
  const int L = tid & 63, w = tid >> 6;
  const int wm = w & 1, wn = w >> 1;
  const int quad = L >> 4, lo = L & 15;

  __shared__ unsigned short As[128 * 32];  // 8 KB, no pad (glds contiguity)
  __shared__ unsigned short Bs[128 * 32];

  const unsigned short* Ab = Xp + (size_t)kh * 1048576 + (size_t)mt * 128 * 1024;
  const unsigned short* Bb = Wb + (size_t)dk * 2097152 + (size_t)ntl * 128 * 1024;

  floatx4 acc[4][4] = {};

  for (int kc = 0; kc < 32; ++kc) {
#pragma unroll
    for (int q = 0; q < 2; ++q) {
      int c = q * 256 + w * 64 + L;  // 16B chunk id, 0..511
      int ldsb = (q * 256 + w * 64) * 8;  // wave-uniform base (shorts)
      GLOAD_LDS16(Ab + (size_t)(c >> 2) * 1024 + kc * 32 + (c & 3) * 8, As + ldsb);
      GLOAD_LDS16(Bb + (size_t)(c >> 2) * 1024 + kc * 32 + (c & 3) * 8, Bs + ldsb);
    }
    __syncthreads();  // implicit vmcnt(0): LDS tiles ready
    short8 af[4], bf[4];
#pragma unroll
    for (int mi = 0; mi < 4; ++mi)
      af[mi] = *(const short8*)(As + (wm * 64 + mi * 16 + lo) * 32 + quad * 8);
#pragma unroll
    for (int ni = 0; ni < 4; ++ni)
      bf[ni] = *(const short8*)(Bs + (wn * 64 + ni * 16 + lo) * 32 + quad * 8);
#pragma unroll
    for (int mi = 0; mi < 4; ++mi)
#pragma unroll
      for (int ni = 0; ni < 4; ++ni)
        acc[mi][ni] = __builtin_amdgcn_mfma_f32_16x16x32_bf16(af[mi], bf[ni], acc[mi][ni], 0, 0, 0);
    __syncthreads();  // LDS reads done before next stage
  }

#pragma unroll
  for (int mi = 0; mi < 4; ++mi)
#pragma unroll
    for (int ni = 0; ni < 4; ++ni) {
      int g = ntl * 128 + wn * 64 + ni * 16 + lo;
      float bv = bias[dk * 2048 + g];
#pragma unroll
      for (int r = 0; r < 4; ++r) {
        int m = mt * 128 + wm * 64 + mi * 16 + quad * 4 + r;  // row=(L>>4)*4+r, col=L&15
        ih[((size_t)dk * 1024 + m) * 2048 + g] = acc[mi][ni][r] + bv;
      }
    }
}

// Persistent recurrence. grid=128: group = blockIdx&7, wg = blockIdx>>3 owns
// h-cols [wg*32, wg*32+32). Wave w = gate (i,f,g,o), 2 N-tiles each.
// stateS[grp][s][8][128] ull: slot s = h input for step s; poison-polled.
__global__ __launch_bounds__(256) void lstm_rec_k(
    const float* __restrict__ ih, const unsigned short* __restrict__ whh,
    float* __restrict__ out, ull* __restrict__ stateS) {
  const int tid = threadIdx.x;
  const int L = tid & 63;
  const int w = tid >> 6;
  const int grp = blockIdx.x & 7;
  const int d = grp >> 2, kh = grp & 3;
  const int wg = blockIdx.x >> 3;
  const int j0 = wg * 32;
  const int quad = L >> 4, lo = L & 15;

  __shared__ unsigned short h_lds[16 * 520];  // rows 8..15 stay zero (M-pad)
  __shared__ float gbuf[4][8][32];            // [gate][b][jj]

  for (int i = tid; i < 16 * 520; i += 256) h_lds[i] = 0;

  // Whh slice -> register B-frags: wave w, gate rows g = w*512 + j0 + ni*16 + lo
  short8 bfrag[2][16];
#pragma unroll
  for (int ni = 0; ni < 2; ++ni) {
    const unsigned short* wb =
        whh + ((size_t)grp * 2048 + (size_t)(w * 512 + j0 + ni * 16 + lo)) * 512 + quad * 8;
#pragma unroll
    for (int kk = 0; kk < 16; ++kk) bfrag[ni][kk] = *(const short8*)(wb + kk * 32);
  }

  const int pb = tid >> 5, pjj = tid & 31;  // pointwise cell (b, jj)
  float creg = 0.0f;

  // prefetch ih gates for s=0
  float ihv[2][4];
  {
    int t0 = d ? 127 : 0;
#pragma unroll
    for (int ni = 0; ni < 2; ++ni) {
      const float* ihp =
          ih + ((size_t)grp * 1024 + (size_t)t0 * 8) * 2048 + (w * 512 + j0 + ni * 16 + lo);
#pragma unroll
      for (int r = 0; r < 4; ++r) {
        int b = quad * 4 + r;
        ihv[ni][r] = (b < 8) ? ihp[(size_t)b * 2048] : 0.0f;
      }
    }
  }

  const int srow = tid >> 5;         // batch row 0..7
  const int scol = (tid & 31) * 16;  // h-col base within row (elements)

  for (int s = 0; s < 128; ++s) {
    const int t = d ? (127 - s) : s;

    if (s) {  // stage h_prev: poll slot s until this thread's producer wrote it
      const ull* src = stateS + ((size_t)grp * 128 + s) * 1024 + tid * 4;
      ull v0, v1, v2, v3;
      do {
        v0 = __hip_atomic_load(src + 0, __ATOMIC_RELAXED, __HIP_MEMORY_SCOPE_AGENT);
        v1 = __hip_atomic_load(src + 1, __ATOMIC_RELAXED, __HIP_MEMORY_SCOPE_AGENT);
        v2 = __hip_atomic_load(src + 2, __ATOMIC_RELAXED, __HIP_MEMORY_SCOPE_AGENT);
        v3 = __hip_atomic_load(src + 3, __ATOMIC_RELAXED, __HIP_MEMORY_SCOPE_AGENT);
      } while (v0 == POISON || v1 == POISON || v2 == POISON || v3 == POISON);
      unsigned short* dl = h_lds + srow * 520 + scol;
      *(ull*)(dl + 0) = v0;
      *(ull*)(dl + 4) = v1;
      *(ull*)(dl + 8) = v2;
      *(ull*)(dl + 12) = v3;
    }
    __syncthreads();

    floatx4 acc[2] = {};
    {  // A[m][k]: m = L&15 (batch, rows 8..15 zero), k = kk*32 + quad*8 + j
      const unsigned short* ar = h_lds + lo * 520 + quad * 8;
#pragma unroll
      for (int kk = 0; kk < 16; ++kk) {
        short8 a = *(const short8*)(ar + kk * 32);
#pragma unroll
        for (int ni = 0; ni < 2; ++ni)
          acc[ni] = __builtin_amdgcn_mfma_f32_16x16x32_bf16(a, bfrag[ni][kk], acc[ni], 0, 0, 0);
      }
    }
#pragma unroll
    for (int ni = 0; ni < 2; ++ni)
#pragma unroll
      for (int r = 0; r < 4; ++r) {
        int b = quad * 4 + r;
        if (b < 8) gbuf[w][b][ni * 16 + lo] = acc[ni][r] + ihv[ni][r];
      }

    if (s < 127) {  // prefetch ih for s+1 (flies during pointwise + next poll)
      int tn = d ? (126 - s) : (s + 1);
#pragma unroll
      for (int ni = 0; ni < 2; ++ni) {
        const float* ihp =
            ih + ((size_t)grp * 1024 + (size_t)tn * 8) * 2048 + (w * 512 + j0 + ni * 16 + lo);
#pragma unroll
        for (int r = 0; r < 4; ++r) {
          int b = quad * 4 + r;
          ihv[ni][r] = (b < 8) ? ihp[(size_t)b * 2048] : 0.0f;
        }
      }
    }
    __syncthreads();

    // pointwise LSTM cell: one (b, jj) per thread
    {
      float ig = gbuf[0][pb][pjj], fg = gbuf[1][pb][pjj];
      float gg = gbuf[2][pb][pjj], og = gbuf[3][pb][pjj];
      float cn = sigm(fg) * creg + sigm(ig) * tanh_f(gg);
      creg = cn;
      float h = sigm(og) * tanh_f(cn);

      if (s < 127) {  // publish h into slot s+1: shfl-pack 4 lanes -> 8B store
        unsigned hs = f2bf(h);
        int base = L & ~3;
        unsigned v0 = __shfl(hs, base + 0);
        unsigned v1 = __shfl(hs, base + 1);
        unsigned v2 = __shfl(hs, base + 2);
        unsigned v3 = __shfl(hs, base + 3);
        if ((L & 3) == 0) {
          ull wv = (ull)v0 | ((ull)v1 << 16) | ((ull)v2 << 32) | ((ull)v3 << 48);
          ull* dst = stateS + ((size_t)grp * 128 + (s + 1)) * 1024 + pb * 128 + ((j0 + pjj) >> 2);
          __hip_atomic_store(dst, wv, __ATOMIC_RELAXED, __HIP_MEMORY_SCOPE_AGENT);
        }
      }
      out[(((size_t)pb * 128 + t) * 1024 + d * 512 + j0 + pjj) * 4 + kh] = h;
    }
  }
}

extern "C" void kernel_launch(void* const* d_in, const int* in_sizes, int n_in,
                              void* d_out, int out_size, void* d_ws, size_t ws_size,
                              hipStream_t stream) {
  (void)in_sizes; (void)n_in; (void)out_size; (void)ws_size;
  const float* x     = (const float*)d_in[0];
  const float* Wih_f = (const float*)d_in[1];
  const float* Whh_f = (const float*)d_in[2];
  const float* bih_f = (const float*)d_in[3];
  const float* bhh_f = (const float*)d_in[4];
  const float* Wih_b = (const float*)d_in[5];
  const float* Whh_b = (const float*)d_in[6];
  const float* bih_b = (const float*)d_in[7];
  const float* bhh_b = (const float*)d_in[8];
  float* out = (float*)d_out;
  char* ws = (char*)d_ws;

  float* bias          = (float*)(ws + (256u << 10));           // 64 KB
  float* ihg           = (float*)(ws + (1ull << 20));           // 64 MB fp32 ih gates
  unsigned short* Xp   = (unsigned short*)(ws + (65ull << 20)); // 8 MB
  unsigned short* Wihb = (unsigned short*)(ws + (73ull << 20)); // 32 MB
  unsigned short* Whhb = (unsigned short*)(ws + (65ull << 20)); // 16 MB (post-GEMM overlay)
  ull* stateS          = (ull*)(ws + (81ull << 20));            // 8 MB (post-GEMM overlay)

  pack_x_k<<<4096, 256, 0, stream>>>(x, Xp);
  cast_bf_k<<<8192, 256, 0, stream>>>(Wih_f, Wihb, 2097152);
  cast_bf_k<<<8192, 256, 0, stream>>>(Wih_b, Wihb + 8388608, 2097152);
  bias_k<<<64, 256, 0, stream>>>(bih_f, bhh_f, bih_b, bhh_b, bias);
  gemm_ih_k<<<dim3(8, 16, 8), 256, 0, stream>>>(Xp, Wihb, bias, ihg);
  cast_bf_k<<<4096, 256, 0, stream>>>(Whh_f, Whhb, 1048576);
  cast_bf_k<<<4096, 256, 0, stream>>>(Whh_b, Whhb + 4194304, 1048576);
  fill_poison_k<<<4096, 256, 0, stream>>>(stateS);
  lstm_rec_k<<<128, 256, 0, stream>>>(ihg, Whhb, out, stateS);
}